// Round 3
// baseline (2252.163 us; speedup 1.0000x reference)
//
#include <hip/hip_runtime.h>

// ---------------------------------------------------------------------------
// InteractionBlock: W = ssp(attr@w1+b1)@w2+b2; W *= cutoff(len);
// h = x@lin1_w; agg[dst] += h[src]*W; out = ssp(agg@lin2_w+b)@lin_w+b
// N=50000, E=1.6M, HID=NF=128, NG=64
// R3: layer-1 computed transposed (operand swap) so layer1->layer2 handoff is
//     8 shfl + 4 selects per K-chunk (no LDS tseg round-trip, no conflicts);
//     LDS 53 KB -> 3 blocks/CU (24 waves). Node/out GEMMs: 1 broadcast
//     ds_read_b128 per k (2 cols x 4 rows per thread).
// ---------------------------------------------------------------------------

typedef __attribute__((ext_vector_type(8))) short bf16x8;
typedef __attribute__((ext_vector_type(4))) float f32x4;

static __device__ __forceinline__ float sspf(float v) {
    return fmaxf(v, 0.0f) + __logf(1.0f + __expf(-fabsf(v))) - 0.69314718f;
}

// fp32 -> bf16 round-to-nearest-even
static __device__ __forceinline__ short bf16s(float x) {
    unsigned u = __builtin_bit_cast(unsigned, x);
    return (short)((u + 0x7fffu + ((u >> 16) & 1u)) >> 16);
}
static __device__ __forceinline__ int packbf(float lo, float hi) {
    return (int)(((unsigned)(unsigned short)bf16s(lo)) |
                 (((unsigned)(unsigned short)bf16s(hi)) << 16));
}

// ---------------------------------------------------------------------------
// Kernel 1: h = x @ lin1_w   [N,128] = [N,128]@[128,128]  (fp32 vector)
// Thread owns cols (c0, c0+64) x rows 4rg..4rg+3; per k: one wave-broadcast
// ds_read_b128 + 2 broadcast w loads + 8 FMA.
// ---------------------------------------------------------------------------
__global__ __launch_bounds__(256) void node_proj_kernel(
    const float* __restrict__ x, const float* __restrict__ w,
    float* __restrict__ h, int n)
{
    __shared__ float xsT[128 * 20];   // [k][row], pitch 20 floats
    int row0 = blockIdx.x * 16;
    for (int i = threadIdx.x; i < 2048; i += 256) {
        int r = i >> 7, c = i & 127;
        int rr = row0 + r;
        xsT[c * 20 + r] = (rr < n) ? x[(size_t)rr * 128 + c] : 0.0f;
    }
    __syncthreads();
    int c0 = threadIdx.x & 63, c1 = c0 + 64;
    int rg = threadIdx.x >> 6;        // row group: rows 4rg..4rg+3
    float acc[8] = {0, 0, 0, 0, 0, 0, 0, 0};
    for (int k = 0; k < 128; ++k) {
        float4 xv = *(const float4*)&xsT[k * 20 + 4 * rg];
        float w0 = w[k * 128 + c0];
        float w1v = w[k * 128 + c1];
        acc[0] = fmaf(xv.x, w0, acc[0]);
        acc[1] = fmaf(xv.y, w0, acc[1]);
        acc[2] = fmaf(xv.z, w0, acc[2]);
        acc[3] = fmaf(xv.w, w0, acc[3]);
        acc[4] = fmaf(xv.x, w1v, acc[4]);
        acc[5] = fmaf(xv.y, w1v, acc[5]);
        acc[6] = fmaf(xv.z, w1v, acc[6]);
        acc[7] = fmaf(xv.w, w1v, acc[7]);
    }
#pragma unroll
    for (int r = 0; r < 4; ++r) {
        int rr = row0 + 4 * rg + r;
        if (rr < n) {
            h[(size_t)rr * 128 + c0] = acc[r];
            h[(size_t)rr * 128 + c1] = acc[4 + r];
        }
    }
}

// ---------------------------------------------------------------------------
// Kernel 2: fused edge MLP (MFMA) + cutoff + gather/scatter.
// 512 threads = 8 waves/block; each wave does 16 edges per group iteration.
// mfma_f32_16x16x32_bf16: A[m=lane&15][k=8q+j], B[k=8q+j][n=lane&15],
//                         D[row=4q+r][col=lane&15]  (q = lane>>4).
// Layer 1 computed transposed: D1[c][edge] = (w1^T @ attr^T); layer-2 A-frag
// assembled from D1 via 8 ds_bpermute + 4 selects per 32-k chunk.
// ---------------------------------------------------------------------------
__global__ __launch_bounds__(512, 6) void edge_kernel(
    const float* __restrict__ eattr, const int* __restrict__ eidx,
    const float* __restrict__ elen,
    const float* __restrict__ w1, const float* __restrict__ b1,
    const float* __restrict__ w2, const float* __restrict__ b2,
    const float* __restrict__ h, float* __restrict__ agg, int E)
{
    __shared__ short w1T[128 * 72];    // w1T[c][k], k<64   : 18 KB
    __shared__ short w2T[128 * 136];   // w2T[c][k], k<128  : 34 KB
    __shared__ float b1s[128];
    __shared__ float b2s[128];

    for (int i = threadIdx.x; i < 64 * 128; i += 512) {
        int k = i >> 7, c = i & 127;
        w1T[c * 72 + k] = bf16s(w1[i]);
    }
    for (int i = threadIdx.x; i < 128 * 128; i += 512) {
        int k = i >> 7, c = i & 127;
        w2T[c * 136 + k] = bf16s(w2[i]);
    }
    if (threadIdx.x < 128) {
        b1s[threadIdx.x] = b1[threadIdx.x];
        b2s[threadIdx.x] = b2[threadIdx.x];
    }
    __syncthreads();

    const int lane = threadIdx.x & 63;
    const int m = lane & 15;
    const int q = lane >> 4;
    const int s_ = q & 1;
    const int L0 = 32 * s_ + m;     // src lane for low half of A-frag
    const int L1 = L0 + 16;
    const bool hiTile = (q >= 2);

    const int ngroups = (E + 15) >> 4;
    int wid = blockIdx.x * 8 + (threadIdx.x >> 6);
    int stride = gridDim.x * 8;

    for (int g = wid; g < ngroups; g += stride) {
        int e0 = g << 4;

        // ---- attr fragments (B operand): row e0+m, k = 32a + 8q + j
        int erow = e0 + m;
        if (erow >= E) erow = E - 1;
        const float* ap = eattr + (size_t)erow * 64 + q * 8;
        float4 x0 = *(const float4*)(ap);
        float4 x1 = *(const float4*)(ap + 4);
        float4 x2 = *(const float4*)(ap + 32);
        float4 x3 = *(const float4*)(ap + 36);
        bf16x8 af0, af1;
        af0[0] = bf16s(x0.x); af0[1] = bf16s(x0.y);
        af0[2] = bf16s(x0.z); af0[3] = bf16s(x0.w);
        af0[4] = bf16s(x1.x); af0[5] = bf16s(x1.y);
        af0[6] = bf16s(x1.z); af0[7] = bf16s(x1.w);
        af1[0] = bf16s(x2.x); af1[1] = bf16s(x2.y);
        af1[2] = bf16s(x2.z); af1[3] = bf16s(x2.w);
        af1[4] = bf16s(x3.x); af1[5] = bf16s(x3.y);
        af1[6] = bf16s(x3.z); af1[7] = bf16s(x3.w);

        // ---- layer-2 accumulators (bias added in epilogue)
        f32x4 acc2[8];
#pragma unroll
        for (int nt = 0; nt < 8; ++nt) {
            f32x4 z; z[0] = 0.f; z[1] = 0.f; z[2] = 0.f; z[3] = 0.f;
            acc2[nt] = z;
        }

#pragma unroll
        for (int kc = 0; kc < 4; ++kc) {
            // two layer-1 col-tiles ct2 = 2kc, 2kc+1 (computed transposed)
            int pk[4];
#pragma unroll
            for (int t = 0; t < 2; ++t) {
                int ct2 = 2 * kc + t;
                f32x4 a1; a1[0] = 0.f; a1[1] = 0.f; a1[2] = 0.f; a1[3] = 0.f;
                bf16x8 wA0 = *(const bf16x8*)&w1T[(16 * ct2 + m) * 72 + 8 * q];
                bf16x8 wA1 = *(const bf16x8*)&w1T[(16 * ct2 + m) * 72 + 32 + 8 * q];
                a1 = __builtin_amdgcn_mfma_f32_16x16x32_bf16(wA0, af0, a1, 0, 0, 0);
                a1 = __builtin_amdgcn_mfma_f32_16x16x32_bf16(wA1, af1, a1, 0, 0, 0);
                // lane holds t_pre[edge m][16ct2+4q+r]; add bias, ssp, pack
                float4 bb = *(const float4*)&b1s[16 * ct2 + 4 * q];
                float v0 = sspf(a1[0] + bb.x);
                float v1 = sspf(a1[1] + bb.y);
                float v2 = sspf(a1[2] + bb.z);
                float v3 = sspf(a1[3] + bb.w);
                pk[2 * t]     = packbf(v0, v1);
                pk[2 * t + 1] = packbf(v2, v3);
            }
            // assemble layer-2 A-frag: lane (q,m) needs t[m][32kc+8q+j]
            int fa0 = __shfl(pk[0], L0), fa1 = __shfl(pk[1], L0);
            int fa2 = __shfl(pk[0], L1), fa3 = __shfl(pk[1], L1);
            int fb0 = __shfl(pk[2], L0), fb1 = __shfl(pk[3], L0);
            int fb2 = __shfl(pk[2], L1), fb3 = __shfl(pk[3], L1);
            int4 fr;
            fr.x = hiTile ? fb0 : fa0;
            fr.y = hiTile ? fb1 : fa1;
            fr.z = hiTile ? fb2 : fa2;
            fr.w = hiTile ? fb3 : fa3;
            bf16x8 ta = __builtin_bit_cast(bf16x8, fr);
#pragma unroll
            for (int nt = 0; nt < 8; ++nt) {
                bf16x8 bw2 = *(const bf16x8*)&w2T[(16 * nt + m) * 136 + 32 * kc + 8 * q];
                acc2[nt] = __builtin_amdgcn_mfma_f32_16x16x32_bf16(ta, bw2, acc2[nt], 0, 0, 0);
            }
        }

        // ---- per-edge meta (loaded late to cut live registers in the MLP)
        float cvv[4];
        int sV[4], dV[4];
#pragma unroll
        for (int r = 0; r < 4; ++r) {
            int e = e0 + 4 * q + r;
            int ec = (e < E) ? e : 0;
            float len = elen[ec];
            sV[r] = eidx[ec];
            dV[r] = eidx[E + ec];
            bool ok = (e < E) && (len <= 10.0f) && (len >= 0.0f);
            cvv[r] = ok ? 0.5f * (__cosf(len * 0.31415927f) + 1.0f) : 0.0f;
        }
        float b2l[8];
#pragma unroll
        for (int nt = 0; nt < 8; ++nt) b2l[nt] = b2s[16 * nt + m];

        // ---- epilogue: lane holds W[edge 4q+r][col 16nt+m]
#pragma unroll
        for (int r = 0; r < 4; ++r) {
            float cv = cvv[r];
            if (cv != 0.0f) {
                const float* hp = h + (size_t)sV[r] * 128 + m;
                float* gp = agg + (size_t)dV[r] * 128 + m;
#pragma unroll
                for (int nt = 0; nt < 8; ++nt) {
                    float Wv = (acc2[nt][r] + b2l[nt]) * cv;
                    atomicAdd(gp + nt * 16, hp[nt * 16] * Wv);
                }
            }
        }
    }
}

// ---------------------------------------------------------------------------
// Kernel 3: out = ssp(agg @ lin2_w + lin2_b) @ lin_w + lin_b  (fp32 vector)
// ---------------------------------------------------------------------------
__global__ __launch_bounds__(256) void out_kernel(
    const float* __restrict__ agg,
    const float* __restrict__ w2, const float* __restrict__ b2,
    const float* __restrict__ w3, const float* __restrict__ b3,
    float* __restrict__ out, int n)
{
    __shared__ float aT[128 * 20];   // agg tile transposed [k][row]
    __shared__ float mT[128 * 20];   // mid tile transposed [k][row]
    int row0 = blockIdx.x * 16;
    for (int i = threadIdx.x; i < 2048; i += 256) {
        int r = i >> 7, c = i & 127;
        int rr = row0 + r;
        aT[c * 20 + r] = (rr < n) ? agg[(size_t)rr * 128 + c] : 0.0f;
    }
    __syncthreads();
    int c0 = threadIdx.x & 63, c1 = c0 + 64;
    int rg = threadIdx.x >> 6;

    float acc[8];
    float b0 = b2[c0], b1v = b2[c1];
#pragma unroll
    for (int r = 0; r < 4; ++r) { acc[r] = b0; acc[4 + r] = b1v; }
    for (int k = 0; k < 128; ++k) {
        float4 xv = *(const float4*)&aT[k * 20 + 4 * rg];
        float w0 = w2[k * 128 + c0];
        float w1v = w2[k * 128 + c1];
        acc[0] = fmaf(xv.x, w0, acc[0]);
        acc[1] = fmaf(xv.y, w0, acc[1]);
        acc[2] = fmaf(xv.z, w0, acc[2]);
        acc[3] = fmaf(xv.w, w0, acc[3]);
        acc[4] = fmaf(xv.x, w1v, acc[4]);
        acc[5] = fmaf(xv.y, w1v, acc[5]);
        acc[6] = fmaf(xv.z, w1v, acc[6]);
        acc[7] = fmaf(xv.w, w1v, acc[7]);
    }
    // mid = ssp(acc), store transposed
    float4 s0, s1;
    s0.x = sspf(acc[0]); s0.y = sspf(acc[1]); s0.z = sspf(acc[2]); s0.w = sspf(acc[3]);
    s1.x = sspf(acc[4]); s1.y = sspf(acc[5]); s1.z = sspf(acc[6]); s1.w = sspf(acc[7]);
    *(float4*)&mT[c0 * 20 + 4 * rg] = s0;
    *(float4*)&mT[c1 * 20 + 4 * rg] = s1;
    __syncthreads();

    float b30 = b3[c0], b31 = b3[c1];
#pragma unroll
    for (int r = 0; r < 4; ++r) { acc[r] = b30; acc[4 + r] = b31; }
    for (int k = 0; k < 128; ++k) {
        float4 xv = *(const float4*)&mT[k * 20 + 4 * rg];
        float w0 = w3[k * 128 + c0];
        float w1v = w3[k * 128 + c1];
        acc[0] = fmaf(xv.x, w0, acc[0]);
        acc[1] = fmaf(xv.y, w0, acc[1]);
        acc[2] = fmaf(xv.z, w0, acc[2]);
        acc[3] = fmaf(xv.w, w0, acc[3]);
        acc[4] = fmaf(xv.x, w1v, acc[4]);
        acc[5] = fmaf(xv.y, w1v, acc[5]);
        acc[6] = fmaf(xv.z, w1v, acc[6]);
        acc[7] = fmaf(xv.w, w1v, acc[7]);
    }
#pragma unroll
    for (int r = 0; r < 4; ++r) {
        int rr = row0 + 4 * rg + r;
        if (rr < n) {
            out[(size_t)rr * 128 + c0] = acc[r];
            out[(size_t)rr * 128 + c1] = acc[4 + r];
        }
    }
}

// ---------------------------------------------------------------------------
extern "C" void kernel_launch(void* const* d_in, const int* in_sizes, int n_in,
                              void* d_out, int out_size, void* d_ws, size_t ws_size,
                              hipStream_t stream)
{
    const float* x     = (const float*)d_in[0];
    const int*   eidx  = (const int*)d_in[1];
    const float* elen  = (const float*)d_in[2];
    const float* eattr = (const float*)d_in[3];
    const float* lin1w = (const float*)d_in[4];
    const float* nnw1  = (const float*)d_in[5];
    const float* nnb1  = (const float*)d_in[6];
    const float* nnw2  = (const float*)d_in[7];
    const float* nnb2  = (const float*)d_in[8];
    const float* lin2w = (const float*)d_in[9];
    const float* lin2b = (const float*)d_in[10];
    const float* linw  = (const float*)d_in[11];
    const float* linb  = (const float*)d_in[12];

    int n = in_sizes[0] / 128;   // 50000
    int E = in_sizes[2];         // 1.6M

    float* h   = (float*)d_ws;           // n*128 floats
    float* agg = h + (size_t)n * 128;    // n*128 floats

    hipMemsetAsync(agg, 0, (size_t)n * 128 * sizeof(float), stream);

    node_proj_kernel<<<(n + 15) / 16, 256, 0, stream>>>(x, lin1w, h, n);
    edge_kernel<<<768, 512, 0, stream>>>(eattr, eidx, elen,
                                         nnw1, nnb1, nnw2, nnb2, h, agg, E);
    out_kernel<<<(n + 15) / 16, 256, 0, stream>>>(agg, lin2w, lin2b, linw, linb,
                                                  (float*)d_out, n);
}